// Round 2
// 398.753 us; speedup vs baseline: 1.0199x; 1.0199x over previous
//
#include <hip/hip_runtime.h>

// RotaryPositionEncoding3D: out[b,n,f,c] with f = bin*6 + axis*2 + dup,
// c = 0 (cos) / 1 (sin). Flat within-point index = bin*12 + axis*4 + dup*2 + c.
// One output float4 (= one (point, bin, axis) triple) = (cos, sin, cos, sin).
//
// Round-5: same as round-4 (hoisted invariants + batched loads + nontemporal
// stores) but using a clang native vector type for the store —
// __builtin_nontemporal_store rejects HIP_vector_type<float,4>.

#define UNROLL 8

typedef float vfloat4 __attribute__((ext_vector_type(4)));

__global__ __launch_bounds__(256) void rope3d_kernel(
    const float* __restrict__ xyz,       // [P, 3]
    const float* __restrict__ div_term,  // [32]
    vfloat4* __restrict__ out,           // [P * 96] float4s
    int total_f4)
{
    __shared__ float s_div[32];
    if (threadIdx.x < 32) s_div[threadIdx.x] = div_term[threadIdx.x];
    __syncthreads();

    const int stride = blockDim.x * gridDim.x;   // grid-wide stride, ≡ 0 (mod 96)
    int g = blockIdx.x * blockDim.x + threadIdx.x;

    // One-time decomposition; (bin, axis) invariant because stride % 96 == 0.
    unsigned int ug   = (unsigned int)g;
    unsigned int p    = ug / 96u;          // point index (magic mul, once)
    unsigned int q    = ug - p * 96u;      // [0,96)
    unsigned int bin  = q / 3u;            // frequency bin [0,32), once
    unsigned int axis = q - bin * 3u;      // 0=x 1=y 2=z, once

    const float d       = s_div[bin];      // hoisted LDS read
    const int   cstride = stride >> 5;     // (stride/96)*3 == stride/32
    int         cidx    = (int)(p * 3u + axis);

    if (g + (UNROLL - 1) * stride < total_f4) {
        // Fast path: all 8 iterations in-bounds. Batch the loads first.
        float coord[UNROLL];
#pragma unroll
        for (int k = 0; k < UNROLL; ++k) {
            coord[k] = xyz[cidx];
            cidx += cstride;
        }
#pragma unroll
        for (int k = 0; k < UNROLL; ++k) {
            float ang = coord[k] * d;      // |ang| <= 1
            float s = __sinf(ang);
            float c = __cosf(ang);
            vfloat4 v = {c, s, c, s};
            __builtin_nontemporal_store(v, &out[g]);
            g += stride;
        }
    } else {
        // Tail path (only the last partial stripe of threads).
#pragma unroll
        for (int k = 0; k < UNROLL; ++k) {
            if (g < total_f4) {
                float ang = xyz[cidx] * d;
                float s = __sinf(ang);
                float c = __cosf(ang);
                vfloat4 v = {c, s, c, s};
                __builtin_nontemporal_store(v, &out[g]);
            }
            cidx += cstride;
            g += stride;
        }
    }
}

extern "C" void kernel_launch(void* const* d_in, const int* in_sizes, int n_in,
                              void* d_out, int out_size, void* d_ws, size_t ws_size,
                              hipStream_t stream) {
    const float* xyz      = (const float*)d_in[0];  // [B*N*3]
    const float* div_term = (const float*)d_in[1];  // [32]
    float*       out      = (float*)d_out;          // [B*N*192*2]

    int points   = in_sizes[0] / 3;       // B*N
    int total_f4 = points * 96;           // out_size / 4

    const int block = 256;
    int grid = (total_f4 + block * UNROLL - 1) / (block * UNROLL);
    grid = ((grid + 2) / 3) * 3;          // multiple of 3 -> stride % 96 == 0
    rope3d_kernel<<<grid, block, 0, stream>>>(xyz, div_term, (vfloat4*)out, total_f4);
}